// Round 6
// baseline (169.095 us; speedup 1.0000x reference)
//
#include <hip/hip_runtime.h>

// SpaNn belief-propagation decoder, sparse reformulation (round 8).
// N=1024 vars x DV=4 edges = E=4096; M=512 checks x DC=8.
// var_of_edge[e] = e>>2 (static). Check connectivity recovered from
// w_odd_to_even via each row's leftmost nonzero column f[e]:
// for a check with edges e1<e2<...<e8, f(e1)=e2 and f(ek>=2)=e1, so
//   key(e) = (f(f(e))==e && e<f(e)) ? e : f(e)
// maps every edge to its check's minimum edge.
//
// Round-8 change: BARRIER-FREE TAGGED DATAFLOW. R4/R5 showed each global
// phase boundary costs ~2.5-3 us. Every (iteration, edge) even-message is
// produced exactly once -> it gets a write-once 64-bit slot {MAGIC tag |
// float payload}, stored with ONE relaxed/agent bypass atomic (R3-R5
// validated primitive; poison != MAGIC). Consumers poll their 3 sibling
// slots directly. 5 distinct iteration buffers -> no overwrite, no ABA.
// Dependency graph acyclic (scan -> it0 -> ... -> it4 -> out), all 256
// blocks co-resident (1/CU) -> deadlock-free; bounded polls as a valve.
// f handoff uses the same tagged scheme (sflag deleted). Intra-check odd
// exchange via intra-wave __shfl (8 aligned lanes/check) -> ZERO
// __syncthreads and zero barriers in the BP loop.
// All FP op sequences bitwise-identical to rounds 2-7 (absmax 0.0):
// skipped product/sum factors are replaced by exact *1.0f / +0.0f.

#define En 4096
#define Nn 1024
#define Mn 512
#define EPSF 1.1920929e-07f
#define MAGICI 0x7E57A11F
#define NSOLVE 16
#define CPB (Mn / NSOLVE)  // 32 checks per solver block
#define VPB (Nn / NSOLVE)  // 64 output vars per solver block
#define PBOUND (1 << 18)   // poll safety valve (~100ms >> any legit wait)

typedef unsigned long long u64;

__device__ __forceinline__ u64 ldq_b(const u64* p) {
  return __hip_atomic_load(p, __ATOMIC_RELAXED, __HIP_MEMORY_SCOPE_AGENT);
}
__device__ __forceinline__ void stq_b(u64* p, u64 v) {
  __hip_atomic_store(p, v, __ATOMIC_RELAXED, __HIP_MEMORY_SCOPE_AGENT);
}
__device__ __forceinline__ u64 packf(float f) {
  return ((u64)MAGICI << 32) | (u64)__float_as_uint(f);
}
__device__ __forceinline__ bool tagged(u64 v) { return (v >> 32) == (u64)MAGICI; }
__device__ __forceinline__ float payload(u64 v) { return __uint_as_float((unsigned)v); }

__global__ __launch_bounds__(1024) void spa_fused(
    const float* __restrict__ w, const float* __restrict__ x,
    float* __restrict__ out, u64* __restrict__ fq,
    u64* __restrict__ evq) {
  __shared__ int fs[En];       // 16 KB  leftmost-peer
  __shared__ int slotmap[En];  // 16 KB  min-edge -> check slot
  __shared__ int ce[En];       // 16 KB  check -> 8 edges (ascending)
  __shared__ int cnt[Mn];      //  2 KB  fill position per check
  __shared__ int wtot[16];

  const int t    = threadIdx.x;
  const int lane = t & 63;
  const int wv   = t >> 6;
  const int b    = blockIdx.x;

  // ======== phase 1: every block scans 16 rows, one wave per row ========
  // (scan unchanged from R5; result store is now a self-tagged 64b slot)
  {
    const int row = b * 16 + wv;
    const float4* rowp = (const float4*)(w + (size_t)row * En);
    float4 v0 = rowp[lane];
    float4 v1 = rowp[64 + lane];
    float4 v2 = rowp[128 + lane];
    float4 v3 = rowp[192 + lane];
    for (int base = 0;; base += 256) {
      bool any = (v0.x != 0.0f) | (v0.y != 0.0f) | (v0.z != 0.0f) | (v0.w != 0.0f);
      unsigned long long m = __ballot(any);
      if (m) {
        if (lane == __ffsll(m) - 1) {
          int off = (v0.x != 0.0f) ? 0 : (v0.y != 0.0f) ? 1 : (v0.z != 0.0f) ? 2 : 3;
          stq_b(&fq[row], ((u64)MAGICI << 32) | (u64)(unsigned)(base + 4 * lane + off));
        }
        break;
      }
      v0 = v1; v1 = v2; v2 = v3;
      int nxt = base + 1024;
      if (nxt > En - 256) nxt = En - 256;  // clamp: redundant, never OOB
      v3 = rowp[(nxt >> 2) + lane];
    }
  }
  if (b >= NSOLVE) return;  // scanner blocks retire immediately

  // ======== solver blocks 0..15 ========
  if (t < Mn) cnt[t] = 0;

  // ---- poll the 4 f slots this thread consumes (scan handoff) ----
  u64 q0, q1, q2, q3;
  {
    int gd = 0;
    do {
      q0 = ldq_b(&fq[4 * t + 0]);
      q1 = ldq_b(&fq[4 * t + 1]);
      q2 = ldq_b(&fq[4 * t + 2]);
      q3 = ldq_b(&fq[4 * t + 3]);
    } while (!(tagged(q0) && tagged(q1) && tagged(q2) && tagged(q3)) &&
             ++gd < PBOUND);
  }
  fs[4 * t + 0] = (int)(unsigned)q0;
  fs[4 * t + 1] = (int)(unsigned)q1;
  fs[4 * t + 2] = (int)(unsigned)q2;
  fs[4 * t + 3] = (int)(unsigned)q3;
  __syncthreads();

  // ---- preamble (replicated per solver block; deterministic) ----
  const int fearr[4] = {(int)(unsigned)q0, (int)(unsigned)q1,
                        (int)(unsigned)q2, (int)(unsigned)q3};
  int  keys[4];
  bool ismin[4];
#pragma unroll
  for (int k = 0; k < 4; ++k) {
    int e   = 4 * t + k;
    int fe  = fearr[k];
    int ffe = fs[fe];
    keys[k]  = (ffe == e && e < fe) ? e : fe;  // check's minimum edge
    ismin[k] = (keys[k] == e);
  }
  const unsigned long long ltmask = (1ull << lane) - 1ull;
  int pre = 0;
  int rank[4];
#pragma unroll
  for (int k = 0; k < 4; ++k) {
    unsigned long long bb = __ballot(ismin[k]);
    rank[k] = pre + (int)__popcll(bb & ltmask);
    pre    += (int)__popcll(bb);
  }
  if (lane == 0) wtot[wv] = pre;
  __syncthreads();
  int wbase = 0;
  for (int w2 = 0; w2 < wv; ++w2) wbase += wtot[w2];
#pragma unroll
  for (int k = 0; k < 4; ++k)
    if (ismin[k]) slotmap[4 * t + k] = wbase + rank[k];
  __syncthreads();

#pragma unroll
  for (int k = 0; k < 4; ++k) {
    int c = slotmap[keys[k]];
    int p = atomicAdd(&cnt[c], 1);
    ce[c * 8 + p] = 4 * t + k;
  }
  __syncthreads();

  if (t < Mn) {  // Batcher 8-sorter, registers only (canonicalizes order)
    int4 a = *((int4*)&ce[t * 8]);
    int4 bq = *((int4*)&ce[t * 8 + 4]);
    int s0 = a.x, s1 = a.y, s2 = a.z, s3 = a.w;
    int s4 = bq.x, s5 = bq.y, s6 = bq.z, s7 = bq.w;
#define CEX(p, q) { int lo_ = min(p, q), hi_ = max(p, q); p = lo_; q = hi_; }
    CEX(s0, s1); CEX(s2, s3); CEX(s0, s2); CEX(s1, s3); CEX(s1, s2);
    CEX(s4, s5); CEX(s6, s7); CEX(s4, s6); CEX(s5, s7); CEX(s5, s6);
    CEX(s0, s4); CEX(s2, s6); CEX(s1, s5); CEX(s3, s7);
    CEX(s2, s4); CEX(s3, s5);
    CEX(s1, s2); CEX(s3, s4); CEX(s5, s6);
#undef CEX
    *((int4*)&ce[t * 8])     = make_int4(s0, s1, s2, s3);
    *((int4*)&ce[t * 8 + 4]) = make_int4(s4, s5, s6, s7);
  }
  __syncthreads();

  // ---- per-thread role: thread t < 256 owns edge ce[b*256 + t] ----
  // check = t>>3 within block; its 8 threads are one ALIGNED 8-lane group
  // of one wave -> intra-wave shfl exchange, no __syncthreads needed.
  int   e = 0, ek = 0, kv = 0, vhome = 0, ja = 0, jb = 0, jc = 0;
  float xv = 0.0f, od = 0.0f;
  if (t < 256) {
    e     = ce[b * 256 + t];
    ek    = t & 7;
    vhome = e >> 2;
    kv    = e & 3;
    ja    = (kv == 0) ? 1 : 0;            // ascending var-siblings != kv
    jb    = (kv <= 1) ? 2 : 1;
    jc    = (kv == 3) ? 2 : 3;
    xv    = x[vhome];                     // cached read-only input
    od    = tanhf(0.5f * xv);             // iter-1 odd message (== reference)
  }
  const int gb8 = lane & ~7;

  // ---- 5 BP iterations: zero barriers, write-once tagged slots ----
  for (int it = 0; it < 5; ++it) {
    if (t < 256) {
      // even: leave-one-out product over the check's 8 odd messages
      float fk = (od == 0.0f) ? 1.0f : od;  // reference's zero->identity
      float f0 = __shfl(fk, gb8 + 0), f1 = __shfl(fk, gb8 + 1);
      float f2 = __shfl(fk, gb8 + 2), f3 = __shfl(fk, gb8 + 3);
      float f4 = __shfl(fk, gb8 + 4), f5 = __shfl(fk, gb8 + 5);
      float f6 = __shfl(fk, gb8 + 6), f7 = __shfl(fk, gb8 + 7);
      const float fa[8] = {f0, f1, f2, f3, f4, f5, f6, f7};
      int j0 = (ek == 0) ? 1 : 0;
      float p = fa[j0];                   // == 1.0f*f[j0] bitwise
#pragma unroll
      for (int j = 1; j < 8; ++j)         // ascending; *1.0f (exact) where
        p *= ((j > j0) && (j != ek)) ? fa[j] : 1.0f;  // skipped/self
      if (p >= 1.0f)       p =  1.0f - EPSF;
      else if (p <= -1.0f) p = -1.0f + EPSF;
      stq_b(&evq[it * En + e], packf(2.0f * atanhf(p)));  // single-store publish

      if (it < 4) {
        // odd, consumer-side: poll my edge's 3 var-sibling evs slots
        u64 a0, a1, a2;
        int gd = 0;
        do {
          a0 = ldq_b(&evq[it * En + 4 * vhome + ja]);
          a1 = ldq_b(&evq[it * En + 4 * vhome + jb]);
          a2 = ldq_b(&evq[it * En + 4 * vhome + jc]);
        } while (!(tagged(a0) && tagged(a1) && tagged(a2)) && ++gd < PBOUND);
        float s = 0.0f;                   // ascending 3-term sum (ja<jb<jc)
        s += payload(a0);
        s += payload(a1);
        s += payload(a2);
        od = tanhf(0.5f * (xv + s));
      }
    }
  }

  // ---- output: sigmoid(x + sum of final evens), own 64 vars ----
  if (t < VPB) {
    int v = b * VPB + t;
    u64 a0, a1, a2, a3;
    int gd = 0;
    do {
      a0 = ldq_b(&evq[4 * En + 4 * v + 0]);
      a1 = ldq_b(&evq[4 * En + 4 * v + 1]);
      a2 = ldq_b(&evq[4 * En + 4 * v + 2]);
      a3 = ldq_b(&evq[4 * En + 4 * v + 3]);
    } while (!(tagged(a0) && tagged(a1) && tagged(a2) && tagged(a3)) &&
             ++gd < PBOUND);
    float s4 = ((payload(a0) + payload(a1)) + payload(a2)) + payload(a3);
    float z  = x[v] + s4;
    out[v]   = 1.0f / (1.0f + expf(-z));
  }
}

// ---------------------------------------------------------------------------
extern "C" void kernel_launch(void* const* d_in, const int* in_sizes, int n_in,
                              void* d_out, int out_size, void* d_ws,
                              size_t ws_size, hipStream_t stream) {
  const float* x    = (const float*)d_in[0];  // [1024]
  const float* w_oe = (const float*)d_in[2];  // w_odd_to_even [4096,4096]
  float* out = (float*)d_out;

  u64* fq  = (u64*)d_ws;   // [4096]   tagged leftmost-peer slots (32 KB)
  u64* evq = fq + En;      // [5*4096] tagged even-message slots (160 KB)

  spa_fused<<<dim3(256), dim3(1024), 0, stream>>>(w_oe, x, out, fq, evq);
}

// Round 7
// 164.289 us; speedup vs baseline: 1.0293x; 1.0293x over previous
//
#include <hip/hip_runtime.h>

// SpaNn belief-propagation decoder, sparse reformulation (round 9 =
// reversion to round 7, the verified best at 164.0 us total).
// N=1024 vars x DV=4 edges = E=4096; M=512 checks x DC=8.
// var_of_edge[e] = e>>2 (static). Check connectivity recovered from
// w_odd_to_even via each row's leftmost nonzero column f[e]:
// for a check with edges e1<e2<...<e8, f(e1)=e2 and f(ek>=2)=e1, so
//   key(e) = (f(f(e))==e && e<f(e)) ? e : f(e)
// maps every edge to its check's minimum edge.
//
// Structure (ledger of what was measured):
//  - 256 blocks x 1024 thr, 1 block/CU co-resident. All blocks scan 16
//    rows each (depth-4 prefetch, ballot exit) -> f via RELAXED/AGENT
//    bypass stores (R2 proved RELEASE/ACQUIRE fences cost ~100 us; R3
//    proved relaxed bypass is ~free and correct).
//  - 16 solver blocks each own 32 checks; preamble (ballot-scan slot
//    assignment + Batcher sort) replicated per block (deterministic).
//  - CONSUMER-SIDE ODD PHASE: each edge's odd message has exactly one
//    consumer (its check), so odd updates compute in the consumer block;
//    ods never touches memory; only evs transits globally; 5 token
//    barriers total (R5: 10->5 barriers bought ~6 us).
//  - R6's barrier-free tagged dataflow REGRESSED (+5 us): poll-chain
//    contention beats the amortized 16-token barrier. Not kept.
// Sync: __syncthreads' vmcnt(0) drain orders bypass data-stores before
// write-once MAGIC tokens; fresh poison != MAGIC each iteration.
// All FP op sequences bitwise-identical to the reference (absmax 0.0).

#define En 4096
#define Nn 1024
#define Mn 512
#define EPSF 1.1920929e-07f
#define MAGIC 0x7E57A11F
#define NSOLVE 16
#define CPB (Mn / NSOLVE)  // 32 checks per solver block
#define VPB (Nn / NSOLVE)  // 64 output vars per solver block

__device__ __forceinline__ int ldi_b(const int* p) {
  return __hip_atomic_load(p, __ATOMIC_RELAXED, __HIP_MEMORY_SCOPE_AGENT);
}
__device__ __forceinline__ float ldf_b(const float* p) {
  return __hip_atomic_load(p, __ATOMIC_RELAXED, __HIP_MEMORY_SCOPE_AGENT);
}
__device__ __forceinline__ void sti_b(int* p, int v) {
  __hip_atomic_store(p, v, __ATOMIC_RELAXED, __HIP_MEMORY_SCOPE_AGENT);
}
__device__ __forceinline__ void stf_b(float* p, float v) {
  __hip_atomic_store(p, v, __ATOMIC_RELAXED, __HIP_MEMORY_SCOPE_AGENT);
}

// 16-block token barrier (R3/R4/R5-validated). First __syncthreads lowers
// with s_waitcnt vmcnt(0): all of this block's bypass data-stores are at
// the MALL before the token goes up. Write-once per (barrier, block).
// Deadlock-free: all 16 solver blocks are co-resident (1 block/CU).
__device__ __forceinline__ void gbar(int* arrive, int bar, int t, int b) {
  __syncthreads();
  if (t == 0) sti_b(&arrive[bar * NSOLVE + b], MAGIC);
  if (t < NSOLVE) {
    while (ldi_b(&arrive[bar * NSOLVE + t]) != MAGIC)
      __builtin_amdgcn_s_sleep(1);
  }
  __syncthreads();
}

__global__ __launch_bounds__(1024) void spa_fused(
    const float* __restrict__ w, const float* __restrict__ x,
    float* __restrict__ out, int* __restrict__ f_g,
    int* __restrict__ sflag, float* __restrict__ evs_g,
    int* __restrict__ arrive) {
  __shared__ int   fs[En];       // 16 KB  leftmost-peer
  __shared__ int   slotmap[En];  // 16 KB  min-edge -> check slot
  __shared__ int   ce[En];       // 16 KB  check -> 8 edges (ascending)
  __shared__ int   cnt[Mn];      //  2 KB  fill position per check
  __shared__ int   wtot[16];
  __shared__ float xch[256];     //  1 KB  even-phase product inputs

  const int t    = threadIdx.x;
  const int lane = t & 63;
  const int wv   = t >> 6;
  const int b    = blockIdx.x;

  // ======== phase 1: every block scans 16 rows, one wave per row ========
  // 1 KB chunks, ballot exit, 4 chunks in flight. Every row has 7
  // nonzeros, so leftmost col <= 4089 and the loop terminates by 3840.
  {
    const int row = b * 16 + wv;
    const float4* rowp = (const float4*)(w + (size_t)row * En);
    float4 v0 = rowp[lane];
    float4 v1 = rowp[64 + lane];
    float4 v2 = rowp[128 + lane];
    float4 v3 = rowp[192 + lane];
    for (int base = 0;; base += 256) {
      bool any = (v0.x != 0.0f) | (v0.y != 0.0f) | (v0.z != 0.0f) | (v0.w != 0.0f);
      unsigned long long m = __ballot(any);
      if (m) {
        if (lane == __ffsll(m) - 1) {
          int off = (v0.x != 0.0f) ? 0 : (v0.y != 0.0f) ? 1 : (v0.z != 0.0f) ? 2 : 3;
          sti_b(&f_g[row], base + 4 * lane + off);  // bypass, no fence
        }
        break;
      }
      v0 = v1; v1 = v2; v2 = v3;
      int nxt = base + 1024;
      if (nxt > En - 256) nxt = En - 256;  // clamp: redundant, never OOB
      v3 = rowp[(nxt >> 2) + lane];
    }
  }
  __syncthreads();  // vmcnt(0): block's 16 f-stores are at the MALL
  if (t == 0) sti_b(&sflag[b], MAGIC);
  if (b >= NSOLVE) return;

  // ======== solver blocks 0..15 ========
  if (t < Mn) cnt[t] = 0;

  // wait for all 256 scan blocks (bypass loads, no invalidates)
  if (t < 256) {
    while (ldi_b(&sflag[t]) != MAGIC) __builtin_amdgcn_s_sleep(2);
  }
  __syncthreads();

  // ---- preamble (replicated per solver block; deterministic) ----
  int4 fv;
  fv.x = ldi_b(&f_g[4 * t + 0]);
  fv.y = ldi_b(&f_g[4 * t + 1]);
  fv.z = ldi_b(&f_g[4 * t + 2]);
  fv.w = ldi_b(&f_g[4 * t + 3]);
  *((int4*)&fs[4 * t]) = fv;
  __syncthreads();

  const int fearr[4] = {fv.x, fv.y, fv.z, fv.w};
  int  keys[4];
  bool ismin[4];
#pragma unroll
  for (int k = 0; k < 4; ++k) {
    int e   = 4 * t + k;
    int fe  = fearr[k];
    int ffe = fs[fe];
    keys[k]  = (ffe == e && e < fe) ? e : fe;  // check's minimum edge
    ismin[k] = (keys[k] == e);
  }
  const unsigned long long ltmask = (1ull << lane) - 1ull;
  int pre = 0;
  int rank[4];
#pragma unroll
  for (int k = 0; k < 4; ++k) {
    unsigned long long bb = __ballot(ismin[k]);
    rank[k] = pre + (int)__popcll(bb & ltmask);
    pre    += (int)__popcll(bb);
  }
  if (lane == 0) wtot[wv] = pre;
  __syncthreads();
  int wbase = 0;
  for (int w2 = 0; w2 < wv; ++w2) wbase += wtot[w2];
#pragma unroll
  for (int k = 0; k < 4; ++k)
    if (ismin[k]) slotmap[4 * t + k] = wbase + rank[k];
  __syncthreads();

#pragma unroll
  for (int k = 0; k < 4; ++k) {
    int c = slotmap[keys[k]];
    int p = atomicAdd(&cnt[c], 1);
    ce[c * 8 + p] = 4 * t + k;
  }
  __syncthreads();

  if (t < Mn) {  // Batcher 8-sorter, registers only (canonicalizes order)
    int4 a = *((int4*)&ce[t * 8]);
    int4 bq = *((int4*)&ce[t * 8 + 4]);
    int s0 = a.x, s1 = a.y, s2 = a.z, s3 = a.w;
    int s4 = bq.x, s5 = bq.y, s6 = bq.z, s7 = bq.w;
#define CEX(p, q) { int lo_ = min(p, q), hi_ = max(p, q); p = lo_; q = hi_; }
    CEX(s0, s1); CEX(s2, s3); CEX(s0, s2); CEX(s1, s3); CEX(s1, s2);
    CEX(s4, s5); CEX(s6, s7); CEX(s4, s6); CEX(s5, s7); CEX(s5, s6);
    CEX(s0, s4); CEX(s2, s6); CEX(s1, s5); CEX(s3, s7);
    CEX(s2, s4); CEX(s3, s5);
    CEX(s1, s2); CEX(s3, s4); CEX(s5, s6);
#undef CEX
    *((int4*)&ce[t * 8])     = make_int4(s0, s1, s2, s3);
    *((int4*)&ce[t * 8 + 4]) = make_int4(s4, s5, s6, s7);
  }
  __syncthreads();

  // ---- per-thread role: thread t < 256 owns edge ce[b*256 + t] ----
  // (my checks are b*CPB .. b*CPB+31; their 256 edges are contiguous in ce,
  //  sorted ascending within each check -> group of 8 threads = one check)
  int   e = 0, kv = 0, vhome = 0;
  float xv = 0.0f, od = 0.0f;
  if (t < 256) {
    e     = ce[b * 256 + t];
    vhome = e >> 2;
    kv    = e & 3;
    xv    = x[vhome];               // cached load (read-only input)
    od    = tanhf(0.5f * xv);       // iter-1 odd message (== reference init)
  }

  // ---- 5 BP iterations: even publishes evs, odd is consumer-side ----
  for (int it = 0; it < 5; ++it) {
    // even: leave-one-out product over the check's 8 odd messages
    if (t < 256) xch[t] = (od == 0.0f) ? 1.0f : od;  // zero->identity subst
    __syncthreads();
    if (t < 256) {
      int gb = t & ~7;
      int ek = t & 7;
      int j0 = (ek == 0) ? 1 : 0;
      float p = xch[gb + j0];            // == 1.0f*f[j0] bitwise
      for (int j = j0 + 1; j < 8; ++j)
        if (j != ek) p *= xch[gb + j];   // ascending, skip self (np.prod)
      if (p >= 1.0f)       p =  1.0f - EPSF;
      else if (p <= -1.0f) p = -1.0f + EPSF;
      stf_b(&evs_g[e], 2.0f * atanhf(p));
    }
    gbar(arrive, it, t, b);  // evs(it) globally visible past here

    if (it < 4) {
      // odd, consumer-side: extrinsic sum of my edge's 3 siblings
      if (t < 256) {
        float s = 0.0f;
        for (int j = 0; j < 4; ++j)
          if (j != kv) s += ldf_b(&evs_g[4 * vhome + j]);  // ascending
        od = tanhf(0.5f * (xv + s));
      }
    }
  }

  // ---- output: sigmoid(x + sum of final evens), own 64 vars ----
  if (t < VPB) {
    int v = b * VPB + t;
    float e0 = ldf_b(&evs_g[4 * v + 0]);
    float e1 = ldf_b(&evs_g[4 * v + 1]);
    float e2 = ldf_b(&evs_g[4 * v + 2]);
    float e3 = ldf_b(&evs_g[4 * v + 3]);
    float s4 = ((e0 + e1) + e2) + e3;
    float z  = x[v] + s4;
    out[v]   = 1.0f / (1.0f + expf(-z));
  }
}

// ---------------------------------------------------------------------------
extern "C" void kernel_launch(void* const* d_in, const int* in_sizes, int n_in,
                              void* d_out, int out_size, void* d_ws,
                              size_t ws_size, hipStream_t stream) {
  const float* x    = (const float*)d_in[0];  // [1024]
  const float* w_oe = (const float*)d_in[2];  // w_odd_to_even [4096,4096]
  float* out = (float*)d_out;

  int*   f      = (int*)d_ws;             // [4096] leftmost peer per edge
  int*   sflag  = f + En;                 // [256]  scan-done flags
  float* evs_g  = (float*)(sflag + 256);  // [4096] even messages (bypass)
  int*   arrive = (int*)(evs_g + En);     // [5*16] barrier tokens

  spa_fused<<<dim3(256), dim3(1024), 0, stream>>>(w_oe, x, out, f, sflag,
                                                  evs_g, arrive);
}